// Round 3
// baseline (682.655 us; speedup 1.0000x reference)
//
#include <hip/hip_runtime.h>
#include <hip/hip_bf16.h>

#define T_TOK 16384
#define DM 256
#define NE 8
#define HF 512

typedef __bf16 bf16x8 __attribute__((ext_vector_type(8)));
typedef float f32x4 __attribute__((ext_vector_type(4)));

__device__ __forceinline__ unsigned short f2bf(float f) {
  unsigned u = __float_as_uint(f);
  u += 0x7fffu + ((u >> 16) & 1u);  // RNE
  return (unsigned short)(u >> 16);
}

// ---- gate: thread=(token,expert), fp64 scores, top-2, list build, out=b2 init ----
__global__ __launch_bounds__(256) void gate_kernel(
    const float* __restrict__ x, const float* __restrict__ Wg,
    const float* __restrict__ bg, const float* __restrict__ b2,
    int* __restrict__ cnts, int* __restrict__ list, float* __restrict__ out) {
  __shared__ int hist[NE], base_s[NE], rank[NE];
  int tid = threadIdx.x;
  if (tid < NE) { hist[tid] = 0; rank[tid] = 0; }
  __syncthreads();

  int tl = tid >> 3, e = tid & 7, lane = tid & 63;
  int t = blockIdx.x * 32 + tl;
  const float* xr = x + (size_t)t * DM;
  double a0 = 0, a1 = 0, a2 = 0, a3 = 0;
  for (int d = 0; d < DM; d += 4) {
    float4 v = *reinterpret_cast<const float4*>(xr + d);
    a0 += (double)v.x * (double)Wg[(d + 0) * NE + e];
    a1 += (double)v.y * (double)Wg[(d + 1) * NE + e];
    a2 += (double)v.z * (double)Wg[(d + 2) * NE + e];
    a3 += (double)v.w * (double)Wg[(d + 3) * NE + e];
  }
  double s = ((a0 + a1) + (a2 + a3)) + (double)bg[e];

  // gather all 8 scores of this token (8-lane aligned groups within the wave)
  double sc[8];
#pragma unroll
  for (int k = 0; k < 8; k++) sc[k] = __shfl(s, (lane & 56) | k);
  int e1 = 0;
#pragma unroll
  for (int k = 1; k < 8; k++) if (sc[k] > sc[e1]) e1 = k;  // ties -> lower index
  int e2 = -1;
#pragma unroll
  for (int k = 0; k < 8; k++) {
    if (k == e1) continue;
    if (e2 < 0 || sc[k] > sc[e2]) e2 = k;
  }

  if (e == 0) { atomicAdd(&hist[e1], 1); atomicAdd(&hist[e2], 1); }
  __syncthreads();
  if (tid < NE) base_s[tid] = atomicAdd(&cnts[tid], hist[tid]);
  __syncthreads();
  if (e == 0) {
    int r1 = atomicAdd(&rank[e1], 1);
    list[e1 * T_TOK + base_s[e1] + r1] = t;
    int r2 = atomicAdd(&rank[e2], 1);
    list[e2 * T_TOK + base_s[e2] + r2] = t;
  }

  // initialize out row with b2[e1]+b2[e2] (replaces memset; FFN only atomicAdds)
  const float* p1 = b2 + e1 * DM + e * 32;
  const float* p2 = b2 + e2 * DM + e * 32;
  float* orow = out + (size_t)t * DM + e * 32;
#pragma unroll
  for (int j = 0; j < 32; j += 4) {
    float4 u = *reinterpret_cast<const float4*>(p1 + j);
    float4 v = *reinterpret_cast<const float4*>(p2 + j);
    float4 o;
    o.x = u.x + v.x; o.y = u.y + v.y; o.z = u.z + v.z; o.w = u.w + v.w;
    *reinterpret_cast<float4*>(orow + j) = o;
  }
}

// ---------------- transpose+cast: in fp32 [R][C] per slab -> out bf16 [C][R] ------
__global__ __launch_bounds__(256) void transpose_kernel(
    const float* __restrict__ in, unsigned short* __restrict__ out, int R, int C) {
  __shared__ float tile[32][33];
  int z = blockIdx.z;
  const float* src = in + (size_t)z * R * C;
  unsigned short* dst = out + (size_t)z * R * C;
  int c0 = blockIdx.x * 32, r0 = blockIdx.y * 32;
  int tx = threadIdx.x, ty = threadIdx.y;  // (32,8)
#pragma unroll
  for (int i = 0; i < 4; i++)
    tile[ty + i * 8][tx] = src[(size_t)(r0 + ty + i * 8) * C + c0 + tx];
  __syncthreads();
#pragma unroll
  for (int i = 0; i < 4; i++)
    dst[(size_t)(c0 + ty + i * 8) * R + r0 + tx] = f2bf(tile[tx][ty + i * 8]);
}

// ---- FFN: 64-token tile, 4 independent waves each owning a 128-wide h-slice ------
// GEMM1: m=h (A=W1 rows from w1t[E][H][D]), n=token (B=X frags in LDS), k=D.
// H stays in registers (C col=token matches B-frag lane layout; h remapped via shfl).
// GEMM2: m=d (A=W2 rows from w2t[E][D][H]), n=token (B=H regs), k=h-slice.
// Partial outputs combined with atomicAdd (4 waves x 2 experts per out element).
__global__ __launch_bounds__(256, 2) void ffn_kernel(
    const float* __restrict__ x, const unsigned short* __restrict__ w1t,
    const float* __restrict__ b1, const unsigned short* __restrict__ w2t,
    const int* __restrict__ cnts, const int* __restrict__ list,
    float* __restrict__ out) {
  __shared__ __align__(16) unsigned short Xf[32 * 64 * 8];  // 32 KB, fragment-order
  __shared__ int tok_s[64];

  int e = blockIdx.x >> 8;
  int tile = blockIdx.x & 255;
  int cnt = cnts[e];
  int base = tile * 64;
  if (base >= cnt) return;

  int tid = threadIdx.x;
  int w = tid >> 6, lane = tid & 63;
  int quad = lane >> 4, l16 = lane & 15;

  {  // ---- stage X fragments: warp w stages n-tile nt=w (lane-linear LDS writes) ----
    int tl = w * 16 + l16;
    int token = (base + tl < cnt) ? list[e * T_TOK + base + tl] : -1;
    if (quad == 0) tok_s[tl] = token;
    unsigned short* dst0 = Xf + ((size_t)w * 8 * 64 + lane) * 8;
    if (token >= 0) {
      const float* xr = x + (size_t)token * DM + quad * 8;
#pragma unroll
      for (int ks = 0; ks < 8; ks++) {
        float4 v0 = *reinterpret_cast<const float4*>(xr + ks * 32);
        float4 v1 = *reinterpret_cast<const float4*>(xr + ks * 32 + 4);
        uint4 pk;
        pk.x = (unsigned)f2bf(v0.x) | ((unsigned)f2bf(v0.y) << 16);
        pk.y = (unsigned)f2bf(v0.z) | ((unsigned)f2bf(v0.w) << 16);
        pk.z = (unsigned)f2bf(v1.x) | ((unsigned)f2bf(v1.y) << 16);
        pk.w = (unsigned)f2bf(v1.z) | ((unsigned)f2bf(v1.w) << 16);
        *reinterpret_cast<uint4*>(dst0 + ks * 512) = pk;
      }
    } else {
      uint4 z = {0, 0, 0, 0};
#pragma unroll
      for (int ks = 0; ks < 8; ks++)
        *reinterpret_cast<uint4*>(dst0 + ks * 512) = z;
    }
  }
  __syncthreads();  // the ONLY block-wide barrier

  const unsigned short* w1e = w1t + (size_t)e * HF * DM;
  const unsigned short* w2e = w2t + (size_t)e * DM * HF;
  int h0 = w * 128;

  unsigned hfr[4][4][4];  // [nt][ks2][dword] : H as GEMM2 B-fragments, 64 VGPRs

  for (int hh = 0; hh < 2; hh++) {
    f32x4 pacc[4][4];  // [mt][nt]
#pragma unroll
    for (int mt = 0; mt < 4; mt++)
#pragma unroll
      for (int nt = 0; nt < 4; nt++) pacc[mt][nt] = (f32x4){0.f, 0.f, 0.f, 0.f};

#pragma unroll
    for (int ks = 0; ks < 8; ks++) {
      bf16x8 xb[4];
#pragma unroll
      for (int nt = 0; nt < 4; nt++)
        xb[nt] = *reinterpret_cast<const bf16x8*>(Xf + ((nt * 8 + ks) * 64 + lane) * 8);
#pragma unroll
      for (int mt = 0; mt < 4; mt++) {
        bf16x8 af = *reinterpret_cast<const bf16x8*>(
            w1e + (size_t)(h0 + hh * 64 + mt * 16 + l16) * DM + ks * 32 + quad * 8);
#pragma unroll
        for (int nt = 0; nt < 4; nt++)
          pacc[mt][nt] = __builtin_amdgcn_mfma_f32_16x16x32_bf16(af, xb[nt], pacc[mt][nt], 0, 0, 0);
      }
    }

    // bias + exact gelu + pack to bf16 pairs
    unsigned pk[4][4][2];  // [mt][nt][r-pair]
#pragma unroll
    for (int mt = 0; mt < 4; mt++) {
      float bb[4];
#pragma unroll
      for (int r = 0; r < 4; r++)
        bb[r] = b1[e * HF + h0 + hh * 64 + mt * 16 + quad * 4 + r];
#pragma unroll
      for (int nt = 0; nt < 4; nt++) {
        float g[4];
#pragma unroll
        for (int r = 0; r < 4; r++) {
          float v = pacc[mt][nt][r] + bb[r];
          g[r] = 0.5f * v * (1.0f + erff(v * 0.70710678118654752f));
        }
        pk[mt][nt][0] = (unsigned)f2bf(g[0]) | ((unsigned)f2bf(g[1]) << 16);
        pk[mt][nt][1] = (unsigned)f2bf(g[2]) | ((unsigned)f2bf(g[3]) << 16);
      }
    }

    // cross-quad exchange into B-fragment registers (ks2 = 2*hh + k2)
#pragma unroll
    for (int k2 = 0; k2 < 2; k2++) {
#pragma unroll
      for (int jp = 0; jp < 4; jp++) {
        int src = (((quad & 1) * 2 + (jp >> 1)) << 4) | l16;  // source lane
        int rp = jp & 1;
#pragma unroll
        for (int nt = 0; nt < 4; nt++) {
          int v0 = __shfl((int)pk[k2 * 2 + 0][nt][rp], src);  // for consumer quad<2
          int v1 = __shfl((int)pk[k2 * 2 + 1][nt][rp], src);  // for consumer quad>=2
          hfr[nt][hh * 2 + k2][jp] = (quad < 2) ? (unsigned)v0 : (unsigned)v1;
        }
      }
    }
  }

  int tokv[4];
#pragma unroll
  for (int nt = 0; nt < 4; nt++) tokv[nt] = tok_s[nt * 16 + l16];

  // GEMM2: d in 4 chunks of 64; k = this wave's 128 h's (register B-frags)
  for (int dc = 0; dc < 4; dc++) {
    f32x4 oacc[4][4];  // [mt][nt]
#pragma unroll
    for (int mt = 0; mt < 4; mt++)
#pragma unroll
      for (int nt = 0; nt < 4; nt++) oacc[mt][nt] = (f32x4){0.f, 0.f, 0.f, 0.f};

#pragma unroll
    for (int ks2 = 0; ks2 < 4; ks2++) {
#pragma unroll
      for (int mt = 0; mt < 4; mt++) {
        bf16x8 af = *reinterpret_cast<const bf16x8*>(
            w2e + (size_t)(dc * 64 + mt * 16 + l16) * HF + h0 + ks2 * 32 + quad * 8);
#pragma unroll
        for (int nt = 0; nt < 4; nt++)
          oacc[mt][nt] = __builtin_amdgcn_mfma_f32_16x16x32_bf16(
              af, *reinterpret_cast<const bf16x8*>(&hfr[nt][ks2][0]), oacc[mt][nt], 0, 0, 0);
      }
    }

#pragma unroll
    for (int nt = 0; nt < 4; nt++) {
      int token = tokv[nt];
      if (token < 0) continue;
      float* orow = out + (size_t)token * DM;
#pragma unroll
      for (int mt = 0; mt < 4; mt++) {
        int d = dc * 64 + mt * 16 + quad * 4;
#pragma unroll
        for (int r = 0; r < 4; r++)
          atomicAdd(&orow[d + r], oacc[mt][nt][r]);
      }
    }
  }
}

extern "C" void kernel_launch(void* const* d_in, const int* in_sizes, int n_in,
                              void* d_out, int out_size, void* d_ws, size_t ws_size,
                              hipStream_t stream) {
  (void)in_sizes; (void)n_in; (void)ws_size; (void)out_size;
  const float* x  = (const float*)d_in[0];
  const float* Wg = (const float*)d_in[1];
  const float* bg = (const float*)d_in[2];
  const float* W1 = (const float*)d_in[3];
  const float* b1 = (const float*)d_in[4];
  const float* W2 = (const float*)d_in[5];
  const float* b2 = (const float*)d_in[6];
  float* out = (float*)d_out;

  char* ws = (char*)d_ws;
  int* cnts = (int*)ws;                                                  // 256 B
  int* list = (int*)(ws + 256);                                          // 512 KB
  unsigned short* w1t = (unsigned short*)(ws + 256 + 524288);            // 2 MB
  unsigned short* w2t = (unsigned short*)(ws + 256 + 524288 + 2097152);  // 2 MB

  hipMemsetAsync(cnts, 0, 256, stream);

  dim3 tb(32, 8);
  hipLaunchKernelGGL(transpose_kernel, dim3(HF / 32, DM / 32, NE), tb, 0, stream,
                     W1, w1t, DM, HF);   // W1 [D][H] -> w1t [H][D]
  hipLaunchKernelGGL(transpose_kernel, dim3(DM / 32, HF / 32, NE), tb, 0, stream,
                     W2, w2t, HF, DM);   // W2 [H][D] -> w2t [D][H]
  hipLaunchKernelGGL(gate_kernel, dim3(T_TOK / 32), dim3(256), 0, stream,
                     x, Wg, bg, b2, cnts, list, out);
  hipLaunchKernelGGL(ffn_kernel, dim3(NE * 256), dim3(256), 0, stream,
                     x, w1t, b1, w2t, cnts, list, out);
}

// Round 4
// 213.513 us; speedup vs baseline: 3.1973x; 3.1973x over previous
//
#include <hip/hip_runtime.h>
#include <hip/hip_bf16.h>

#define T_TOK 16384
#define DM 256
#define NE 8
#define HF 512

typedef __bf16 bf16x8 __attribute__((ext_vector_type(8)));
typedef float f32x4 __attribute__((ext_vector_type(4)));

__device__ __forceinline__ unsigned f2bf(float f) {
  unsigned u = __float_as_uint(f);
  u += 0x7fffu + ((u >> 16) & 1u);  // RNE
  return u >> 16;
}

// ---- gate: thread=(token,expert), fp64 scores, top-2, list build, out=b2 init ----
__global__ __launch_bounds__(256) void gate_kernel(
    const float* __restrict__ x, const float* __restrict__ Wg,
    const float* __restrict__ bg, const float* __restrict__ b2,
    int* __restrict__ cnts, int* __restrict__ list, float* __restrict__ out) {
  __shared__ int hist[NE], base_s[NE], rank[NE];
  int tid = threadIdx.x;
  if (tid < NE) { hist[tid] = 0; rank[tid] = 0; }
  __syncthreads();

  int tl = tid >> 3, e = tid & 7, lane = tid & 63;
  int t = blockIdx.x * 32 + tl;
  const float* xr = x + (size_t)t * DM;
  double a0 = 0, a1 = 0, a2 = 0, a3 = 0;
  for (int d = 0; d < DM; d += 4) {
    float4 v = *reinterpret_cast<const float4*>(xr + d);
    a0 += (double)v.x * (double)Wg[(d + 0) * NE + e];
    a1 += (double)v.y * (double)Wg[(d + 1) * NE + e];
    a2 += (double)v.z * (double)Wg[(d + 2) * NE + e];
    a3 += (double)v.w * (double)Wg[(d + 3) * NE + e];
  }
  double s = ((a0 + a1) + (a2 + a3)) + (double)bg[e];

  double sc[8];
#pragma unroll
  for (int k = 0; k < 8; k++) sc[k] = __shfl(s, (lane & 56) | k);
  int e1 = 0;
#pragma unroll
  for (int k = 1; k < 8; k++) if (sc[k] > sc[e1]) e1 = k;  // ties -> lower index
  int e2 = -1;
#pragma unroll
  for (int k = 0; k < 8; k++) {
    if (k == e1) continue;
    if (e2 < 0 || sc[k] > sc[e2]) e2 = k;
  }

  if (e == 0) { atomicAdd(&hist[e1], 1); atomicAdd(&hist[e2], 1); }
  __syncthreads();
  if (tid < NE) base_s[tid] = atomicAdd(&cnts[tid], hist[tid]);
  __syncthreads();
  if (e == 0) {
    int r1 = atomicAdd(&rank[e1], 1);
    list[e1 * T_TOK + base_s[e1] + r1] = t;
    int r2 = atomicAdd(&rank[e2], 1);
    list[e2 * T_TOK + base_s[e2] + r2] = t;
  }

  // initialize out row with b2[e1]+b2[e2] (replaces memset; FFN only atomicAdds)
  const float* p1 = b2 + e1 * DM + e * 32;
  const float* p2 = b2 + e2 * DM + e * 32;
  float* orow = out + (size_t)t * DM + e * 32;
#pragma unroll
  for (int j = 0; j < 32; j += 4) {
    float4 u = *reinterpret_cast<const float4*>(p1 + j);
    float4 v = *reinterpret_cast<const float4*>(p2 + j);
    float4 o;
    o.x = u.x + v.x; o.y = u.y + v.y; o.z = u.z + v.z; o.w = u.w + v.w;
    *reinterpret_cast<float4*>(orow + j) = o;
  }
}

// ---- fused transpose+cast: W1 [D][H]->w1t[H][D], W2 [H][D]->w2t[D][H], bf16 ------
__global__ __launch_bounds__(256) void transpose_kernel(
    const float* __restrict__ W1, const float* __restrict__ W2,
    unsigned short* __restrict__ w1t, unsigned short* __restrict__ w2t) {
  __shared__ float tile[32][33];
  int bx = blockIdx.x;
  int which = bx >> 10;        // 0: W1 (NE*128 tiles), 1: W2
  int rem = bx & 1023;
  int e = rem >> 7, t = rem & 127;
  const float* src;
  unsigned short* dst;
  int R, C, cx, ry;
  if (which == 0) {
    R = DM; C = HF;
    src = W1 + (size_t)e * R * C; dst = w1t + (size_t)e * R * C;
    cx = t & 15; ry = t >> 4;
  } else {
    R = HF; C = DM;
    src = W2 + (size_t)e * R * C; dst = w2t + (size_t)e * R * C;
    cx = t & 7; ry = t >> 3;
  }
  int c0 = cx * 32, r0 = ry * 32;
  int tx = threadIdx.x & 31, ty = threadIdx.x >> 5;  // (32,8)
#pragma unroll
  for (int i = 0; i < 4; i++)
    tile[ty + i * 8][tx] = src[(size_t)(r0 + ty + i * 8) * C + c0 + tx];
  __syncthreads();
#pragma unroll
  for (int i = 0; i < 4; i++)
    dst[(size_t)(c0 + ty + i * 8) * R + r0 + tx] =
        (unsigned short)f2bf(tile[tx][ty + i * 8]);
}

// ---- FFN: 64-token tile/block, 4 waves, 2 k-phases ------------------------------
// GEMM1 (per phase): m=h (wave's 64-h slice), n=token(64), k=D(256).
//   A = w1t rows (global, k-contiguous), B = Xf (LDS, fragment order, lane-linear).
//   C (h x token) -> gelu -> scattered into Hs in GEMM2-A-fragment order.
// GEMM2 (per phase): m=token(64), n=d (wave's 64-d slice), k=h-phase(256).
//   A = Hs (LDS, lane-linear b128), B = w2t rows (global, k-contiguous).
// Epilogue: coalesced atomicAdd (16 consecutive d per lane group), 2 adds/element.
__global__ __launch_bounds__(256, 2) void ffn_kernel(
    const float* __restrict__ x, const unsigned short* __restrict__ w1t,
    const float* __restrict__ b1, const unsigned short* __restrict__ w2t,
    const int* __restrict__ cnts, const int* __restrict__ list,
    float* __restrict__ out) {
  __shared__ __align__(16) unsigned short Xf[64 * DM];  // 32 KB
  __shared__ __align__(16) unsigned short Hs[64 * 256]; // 32 KB (one k-phase of H)
  __shared__ int tok_s[64];

  int e = blockIdx.x >> 8;
  int tile = blockIdx.x & 255;
  int cnt = cnts[e];
  int base = tile * 64;
  if (base >= cnt) return;

  int tid = threadIdx.x;
  int w = tid >> 6, lane = tid & 63;
  int quad = lane >> 4, l16 = lane & 15;

  {  // ---- stage Xf: wave w stages n-tile nt=w (lane-linear writes) ----
    int tl = w * 16 + l16;
    int token = (base + tl < cnt) ? list[e * T_TOK + base + tl] : -1;
    if (quad == 0) tok_s[tl] = token;
    unsigned short* dst0 = Xf + ((w * 8) * 64 + lane) * 8;
    if (token >= 0) {
      const float* xr = x + (size_t)token * DM + quad * 8;
#pragma unroll
      for (int ks = 0; ks < 8; ks++) {
        float4 v0 = *reinterpret_cast<const float4*>(xr + ks * 32);
        float4 v1 = *reinterpret_cast<const float4*>(xr + ks * 32 + 4);
        uint4 pk;
        pk.x = f2bf(v0.x) | (f2bf(v0.y) << 16);
        pk.y = f2bf(v0.z) | (f2bf(v0.w) << 16);
        pk.z = f2bf(v1.x) | (f2bf(v1.y) << 16);
        pk.w = f2bf(v1.z) | (f2bf(v1.w) << 16);
        *reinterpret_cast<uint4*>(dst0 + ks * 512) = pk;
      }
    } else {
      uint4 z = {0, 0, 0, 0};
#pragma unroll
      for (int ks = 0; ks < 8; ks++)
        *reinterpret_cast<uint4*>(dst0 + ks * 512) = z;
    }
  }
  __syncthreads();

  const unsigned short* w1e = w1t + (size_t)e * HF * DM;
  const unsigned short* w2e = w2t + (size_t)e * DM * HF;

  f32x4 oacc[4][4];  // [mt(token)][nt(d)]
#pragma unroll
  for (int mt = 0; mt < 4; mt++)
#pragma unroll
    for (int nt = 0; nt < 4; nt++) oacc[mt][nt] = (f32x4){0.f, 0.f, 0.f, 0.f};

#pragma unroll
  for (int p = 0; p < 2; p++) {
    // ================= GEMM1: h-slice [p*256 + w*64, +64) =================
    f32x4 pacc[4][4];  // [mtw(h)][nt(token)]
#pragma unroll
    for (int mt = 0; mt < 4; mt++)
#pragma unroll
      for (int nt = 0; nt < 4; nt++) pacc[mt][nt] = (f32x4){0.f, 0.f, 0.f, 0.f};

    const unsigned short* w1p = w1e + (size_t)(p * 256 + w * 64) * DM;
#pragma unroll
    for (int ks = 0; ks < 8; ks++) {
      bf16x8 xb[4];
#pragma unroll
      for (int nt = 0; nt < 4; nt++)
        xb[nt] = *reinterpret_cast<const bf16x8*>(Xf + ((nt * 8 + ks) * 64 + lane) * 8);
#pragma unroll
      for (int mt = 0; mt < 4; mt++) {
        bf16x8 af = *reinterpret_cast<const bf16x8*>(
            w1p + (size_t)(mt * 16 + l16) * DM + ks * 32 + quad * 8);
#pragma unroll
        for (int nt = 0; nt < 4; nt++)
          pacc[mt][nt] = __builtin_amdgcn_mfma_f32_16x16x32_bf16(af, xb[nt], pacc[mt][nt], 0, 0, 0);
      }
    }

    // bias vectors for this wave's h-slice
    float4 bb[4];
#pragma unroll
    for (int mt = 0; mt < 4; mt++)
      bb[mt] = *reinterpret_cast<const float4*>(
          b1 + e * HF + p * 256 + w * 64 + mt * 16 + quad * 4);

    if (p == 1) __syncthreads();  // WAR: all waves done reading Hs (GEMM2 p0)

    // gelu + scatter into Hs (GEMM2 A-frag order): value at
    // (token = nt*16 + l16, h_local = w*64 + mt*16 + quad*4 + r)
#pragma unroll
    for (int mt = 0; mt < 4; mt++) {
      int ks2 = w * 2 + (mt >> 1);
      int rquad = (mt & 1) * 2 + (quad >> 1);
      const float* bbp = reinterpret_cast<const float*>(&bb[mt]);
#pragma unroll
      for (int nt = 0; nt < 4; nt++) {
        float g[4];
#pragma unroll
        for (int r = 0; r < 4; r++) {
          float v = pacc[mt][nt][r] + bbp[r];
          g[r] = 0.5f * v * (1.0f + erff(v * 0.70710678118654752f));
        }
        unsigned short* hp =
            Hs + ((ks2 * 4 + nt) * 64 + rquad * 16 + l16) * 8 + (quad & 1) * 4;
        *reinterpret_cast<unsigned*>(hp) = f2bf(g[0]) | (f2bf(g[1]) << 16);
        *reinterpret_cast<unsigned*>(hp + 2) = f2bf(g[2]) | (f2bf(g[3]) << 16);
      }
    }
    __syncthreads();  // Hs visible

    // ================= GEMM2 partial: d-slice [w*64, +64), k=[p*256,+256) =========
#pragma unroll
    for (int ks = 0; ks < 8; ks++) {
      bf16x8 ha[4];
#pragma unroll
      for (int mt = 0; mt < 4; mt++)
        ha[mt] = *reinterpret_cast<const bf16x8*>(Hs + ((ks * 4 + mt) * 64 + lane) * 8);
#pragma unroll
      for (int nt = 0; nt < 4; nt++) {
        bf16x8 bf = *reinterpret_cast<const bf16x8*>(
            w2e + (size_t)(w * 64 + nt * 16 + l16) * HF + p * 256 + ks * 32 + quad * 8);
#pragma unroll
        for (int mt = 0; mt < 4; mt++)
          oacc[mt][nt] = __builtin_amdgcn_mfma_f32_16x16x32_bf16(ha[mt], bf, oacc[mt][nt], 0, 0, 0);
      }
    }
  }

  // ---- epilogue: coalesced atomics; row = token (uniform per lane group) ----
#pragma unroll
  for (int mt = 0; mt < 4; mt++) {
#pragma unroll
    for (int r = 0; r < 4; r++) {
      int token = tok_s[mt * 16 + quad * 4 + r];
      if (token < 0) continue;
      float* orow = out + (size_t)token * DM + w * 64;
#pragma unroll
      for (int nt = 0; nt < 4; nt++)
        atomicAdd(orow + nt * 16 + l16, oacc[mt][nt][r]);
    }
  }
}

extern "C" void kernel_launch(void* const* d_in, const int* in_sizes, int n_in,
                              void* d_out, int out_size, void* d_ws, size_t ws_size,
                              hipStream_t stream) {
  (void)in_sizes; (void)n_in; (void)ws_size; (void)out_size;
  const float* x  = (const float*)d_in[0];
  const float* Wg = (const float*)d_in[1];
  const float* bg = (const float*)d_in[2];
  const float* W1 = (const float*)d_in[3];
  const float* b1 = (const float*)d_in[4];
  const float* W2 = (const float*)d_in[5];
  const float* b2 = (const float*)d_in[6];
  float* out = (float*)d_out;

  char* ws = (char*)d_ws;
  int* cnts = (int*)ws;                                                  // 256 B
  int* list = (int*)(ws + 256);                                          // 512 KB
  unsigned short* w1t = (unsigned short*)(ws + 256 + 524288);            // 2 MB
  unsigned short* w2t = (unsigned short*)(ws + 256 + 524288 + 2097152);  // 2 MB

  hipMemsetAsync(cnts, 0, 256, stream);

  hipLaunchKernelGGL(gate_kernel, dim3(T_TOK / 32), dim3(256), 0, stream,
                     x, Wg, bg, b2, cnts, list, out);
  hipLaunchKernelGGL(transpose_kernel, dim3(2 * NE * 128), dim3(256), 0, stream,
                     W1, W2, w1t, w2t);
  hipLaunchKernelGGL(ffn_kernel, dim3(NE * 256), dim3(256), 0, stream,
                     x, w1t, b1, w2t, cnts, list, out);
}